// Round 6
// baseline (467.317 us; speedup 1.0000x reference)
//
#include <hip/hip_runtime.h>

#define LOG2E 1.44269504088896340736f
#define QSCALE 0.18033688011112042f  // 0.125 * LOG2E
#define ESHIFT 4.0f                  // fixed exp2 shift, cancels in normalization

typedef __attribute__((ext_vector_type(8))) _Float16 f16x8;
typedef __attribute__((ext_vector_type(2))) __fp16 fp16v2;
typedef __attribute__((ext_vector_type(4))) float f32x4;

// pack two fp32 -> two f16 in ONE instruction (v_cvt_pkrtz_f16_f32)
__device__ __forceinline__ unsigned int pk_f16(float a, float b) {
  union { fp16v2 h; unsigned int u; } x;
  x.h = __builtin_amdgcn_cvt_pkrtz(a, b);
  return x.u;
}

__device__ __forceinline__ void gld_lds16(const void* g, void* l) {
  __builtin_amdgcn_global_load_lds((const __attribute__((address_space(1))) void*)g,
                                   (__attribute__((address_space(3))) void*)l,
                                   16, 0, 0);
}

// ---------------- fused cast x,y fp32 -> f16 ----------------
__global__ __launch_bounds__(256) void cast_xy(const float* __restrict__ x,
                                               const float* __restrict__ y,
                                               _Float16* __restrict__ xb,
                                               _Float16* __restrict__ yb) {
  int i = blockIdx.x * 256 + threadIdx.x;
  const float* in = x; _Float16* out = xb;
  if (i >= 2097152) { in = y; out = yb; i -= 2097152; }
  float4 v = ((const float4*)in)[i];
  uint2 o;
  o.x = pk_f16(v.x, v.y);
  o.y = pk_f16(v.z, v.w);
  ((uint2*)out)[i] = o;
}

// ---------------- mask pre-scale: out = mask * log2(e) - ESHIFT ----------------
__global__ __launch_bounds__(256) void scale_mask(const float* __restrict__ in,
                                                  float* __restrict__ out) {
  int i = blockIdx.x * 256 + threadIdx.x;
  f32x4 v = ((const f32x4*)in)[i];
  ((f32x4*)out)[i] = v * LOG2E - ESHIFT;
}

// ---------------- fused transpose+cast of Wkv, Wq, Wo ----------------
__global__ __launch_bounds__(256) void transpose_cast_all(
    const float* __restrict__ Wkv, const float* __restrict__ Wq,
    const float* __restrict__ Wo, _Float16* __restrict__ wkvt,
    _Float16* __restrict__ wqt, _Float16* __restrict__ wot) {
  __shared__ float t[32][33];
  int tb = blockIdx.x;
  const float* W; _Float16* Wt; int N;
  if (tb < 2048)      { W = Wkv; Wt = wkvt; N = 2048; }
  else if (tb < 3072) { W = Wq;  Wt = wqt;  N = 1024; tb -= 2048; }
  else                { W = Wo;  Wt = wot;  N = 1024; tb -= 3072; }
  const int K = 1024;
  int tilesN = N >> 5;
  int nb = (tb % tilesN) * 32, kb = (tb / tilesN) * 32;
  int j = threadIdx.x & 31, i0 = threadIdx.x >> 5;
  #pragma unroll
  for (int p = 0; p < 4; ++p) {
    int i = i0 + p * 8;
    t[i][j] = W[(size_t)(kb + i) * N + nb + j];
  }
  __syncthreads();
  #pragma unroll
  for (int p = 0; p < 4; ++p) {
    int i = i0 + p * 8;
    Wt[(size_t)(nb + i) * K + kb + j] = (_Float16)t[j][i];
  }
}

// ---------------- GEMM: C(MxN) = A(MxK) @ Bt(NxK)^T + bias (f16 MFMA) -------
// MODE 0: fp32 C out. MODE 1: kv -> K[b,h,s,64] + Vt[b,h,64,s]. MODE 2: q -> Q * QSCALE.
template <int MODE>
__global__ __launch_bounds__(256)
void gemm128(const _Float16* __restrict__ A,
             const _Float16* __restrict__ Bt,
             const float* __restrict__ bias,
             void* __restrict__ out0, void* __restrict__ out1,
             int M, int N, int K) {
  __shared__ __align__(16) _Float16 As[128 * 64];
  __shared__ __align__(16) _Float16 Bs[128 * 64];
  const int tid = threadIdx.x;
  const int bn = blockIdx.x, bm = blockIdx.y;
  const int wave = tid >> 6, lane = tid & 63;
  const int wm = (wave >> 1) * 64, wn = (wave & 1) * 64;
  const int lrow = lane & 15, quad = lane >> 4;
  const int sw = lrow & 7;

  f32x4 acc[4][4];
  #pragma unroll
  for (int i = 0; i < 4; ++i)
    #pragma unroll
    for (int j = 0; j < 4; ++j)
      #pragma unroll
      for (int r = 0; r < 4; ++r) acc[i][j][r] = 0.f;

  const _Float16* Ab = A + (size_t)(bm * 128) * K;
  const _Float16* Bb = Bt + (size_t)(bn * 128) * K;

  for (int k0 = 0; k0 < K; k0 += 64) {
    #pragma unroll
    for (int i = 0; i < 4; ++i) {
      int e = i * 256 + tid;
      int row = e >> 3, gs = (e & 7) ^ (row & 7);
      gld_lds16(Ab + (size_t)row * K + k0 + gs * 8, &As[e * 8]);
    }
    #pragma unroll
    for (int i = 0; i < 4; ++i) {
      int e = i * 256 + tid;
      int row = e >> 3, gs = (e & 7) ^ (row & 7);
      gld_lds16(Bb + (size_t)row * K + k0 + gs * 8, &Bs[e * 8]);
    }
    __builtin_amdgcn_s_waitcnt(0);
    __syncthreads();
    #pragma unroll
    for (int ks = 0; ks < 2; ++ks) {
      f16x8 af[4], bf[4];
      const int g = ((ks * 4 + quad) ^ sw) * 8;
      #pragma unroll
      for (int i = 0; i < 4; ++i)
        af[i] = *(const f16x8*)&As[(wm + i * 16 + lrow) * 64 + g];
      #pragma unroll
      for (int j = 0; j < 4; ++j)
        bf[j] = *(const f16x8*)&Bs[(wn + j * 16 + lrow) * 64 + g];
      #pragma unroll
      for (int i = 0; i < 4; ++i)
        #pragma unroll
        for (int j = 0; j < 4; ++j)
          acc[i][j] = __builtin_amdgcn_mfma_f32_16x16x32_f16(af[i], bf[j], acc[i][j], 0, 0, 0);
    }
    __syncthreads();
  }

  const int col0 = bn * 128 + wn;
  #pragma unroll
  for (int i = 0; i < 4; ++i) {
    const int row0 = bm * 128 + wm + i * 16 + quad * 4;
    const int b = row0 >> 11, s0 = row0 & 2047;
    #pragma unroll
    for (int j = 0; j < 4; ++j) {
      const int cc = j * 16 + lrow;
      const float bv = bias[col0 + cc];
      float v0 = acc[i][j][0] + bv, v1 = acc[i][j][1] + bv;
      float v2 = acc[i][j][2] + bv, v3 = acc[i][j][3] + bv;
      if (MODE == 0) {
        float* C = (float*)out0;
        size_t off = (size_t)row0 * N + col0 + cc;
        C[off] = v0; C[off + N] = v1; C[off + 2 * N] = v2; C[off + 3 * N] = v3;
      } else if (MODE == 1) {
        const int h = col0 >> 7;
        if ((col0 & 64) == 0) {  // K half: K[b,h,s,64]
          _Float16* Kb = (_Float16*)out0;
          size_t base = ((size_t)(b * 16 + h) * 2048 + s0) * 64 + cc;
          Kb[base] = (_Float16)v0; Kb[base + 64] = (_Float16)v1;
          Kb[base + 128] = (_Float16)v2; Kb[base + 192] = (_Float16)v3;
        } else {                 // V half: Vt[b,h,64,s]
          _Float16* Vt = (_Float16*)out1;
          size_t base = ((size_t)(b * 16 + h) * 64 + cc) * 2048 + s0;
          uint2 p; p.x = pk_f16(v0, v1); p.y = pk_f16(v2, v3);
          *(uint2*)&Vt[base] = p;
        }
      } else {  // MODE 2: Q[b,h,s,64] pre-scaled
        const int h = col0 >> 6;
        _Float16* Qb = (_Float16*)out0;
        size_t base = ((size_t)(b * 16 + h) * 2048 + s0) * 64 + cc;
        Qb[base] = (_Float16)(v0 * QSCALE); Qb[base + 64] = (_Float16)(v1 * QSCALE);
        Qb[base + 128] = (_Float16)(v2 * QSCALE); Qb[base + 192] = (_Float16)(v3 * QSCALE);
      }
    }
  }
}

// ---------------- flash attention v5 ----------------
// grid 512; 256 q-rows/block (2 blocks/CU), 4 waves x 64 q.
// K-tile double-buffered LDS with raw s_barrier + manual vmcnt (no full drain);
// V fragments direct-from-global issued at iter top; lsum via ones-row MFMA;
// f16 MFMA + 1-instr packs; exp2 domain with -4 shift folded into mask.
__global__ __launch_bounds__(256, 2)
void attn(const _Float16* __restrict__ Qbuf,
          const _Float16* __restrict__ Kbuf,
          const _Float16* __restrict__ Vtbuf,
          const float* __restrict__ masks,
          _Float16* __restrict__ vals) {
  const int blk = blockIdx.x;
  const int xcd = blk & 7, s = blk >> 3;
  const int qt2 = s & 7;                 // 8 q-tiles of 256
  const int hb = (s >> 3) * 8 + xcd;     // all 8 qt2 of one (b,h) share an XCD
  const int b = hb >> 4, h = hb & 15;
  const int tid = threadIdx.x, lane = tid & 63, w = tid >> 6;
  const int lrow = lane & 15, quad = lane >> 4;
  const int sw = lrow & 7;

  __shared__ __align__(16) _Float16 Ks[2][64 * 64];  // dbuf K tile [key][d] swizzled
  __shared__ __align__(16) _Float16 Ps[256 * 72];    // Q staging (pitch 64) then P^T (pitch 72)

  const _Float16* qp = Qbuf + ((size_t)hb * 2048 + qt2 * 256) * 64;
  const _Float16* kp = Kbuf + (size_t)hb * 2048 * 64;
  const _Float16* vp = Vtbuf + (size_t)hb * 64 * 2048;
  const float* mp = masks + (size_t)(qt2 * 256 + w * 64) * 2048;

  // stage Q (256x64, swizzled) + K tile 0 -> buf 0
  #pragma unroll
  for (int i = 0; i < 8; ++i) {
    int e = i * 256 + tid;
    int row = e >> 3, gs = (e & 7) ^ (row & 7);
    gld_lds16(qp + (size_t)row * 64 + gs * 8, &Ps[e * 8]);
  }
  #pragma unroll
  for (int i = 0; i < 2; ++i) {
    int e = i * 256 + tid;
    int row = e >> 3, gs = (e & 7) ^ (row & 7);
    gld_lds16(kp + (size_t)row * 64 + gs * 8, &Ks[0][e * 8]);
  }
  __syncthreads();  // full drain: Q + K0 staged

  f16x8 qf[4][2];
  #pragma unroll
  for (int iq = 0; iq < 4; ++iq)
    #pragma unroll
    for (int ks = 0; ks < 2; ++ks)
      qf[iq][ks] = *(const f16x8*)&Ps[(w * 64 + iq * 16 + lrow) * 64 + ((ks * 4 + quad) ^ sw) * 8];
  __builtin_amdgcn_s_waitcnt(0xC07F);  // lgkmcnt(0): qf reads retired before Ps reuse

  // ones A-fragment: row m=0 all-ones -> l = sum over keys via MFMA
  f16x8 ones;
  {
    _Float16 o = (lrow == 0) ? (_Float16)1.0f : (_Float16)0.0f;
    #pragma unroll
    for (int r = 0; r < 8; ++r) ones[r] = o;
  }

  f32x4 o_acc[4][4];  // O^T: d = id*16+quad*4+r, q = iq*16+lrow (per wave q-base w*64)
  f32x4 o_l[4];       // l in row m=0 (quad 0, reg 0)
  #pragma unroll
  for (int id = 0; id < 4; ++id)
    #pragma unroll
    for (int iq = 0; iq < 4; ++iq)
      #pragma unroll
      for (int r = 0; r < 4; ++r) o_acc[id][iq][r] = 0.f;
  #pragma unroll
  for (int iq = 0; iq < 4; ++iq)
    #pragma unroll
    for (int r = 0; r < 4; ++r) o_l[iq][r] = 0.f;

  for (int kt = 0; kt < 32; ++kt) {
    const int cur = kt & 1;
    __builtin_amdgcn_s_barrier();  // (A) all waves done reading Ks[cur^1]
    if (kt < 31) {
      #pragma unroll
      for (int i = 0; i < 2; ++i) {  // prefetch K tile kt+1
        int e = i * 256 + tid;
        int row = e >> 3, gs = (e & 7) ^ (row & 7);
        gld_lds16(kp + (size_t)((kt + 1) * 64 + row) * 64 + gs * 8, &Ks[cur ^ 1][e * 8]);
      }
      __builtin_amdgcn_s_waitcnt(0xF72);  // vmcnt(2): Ks[cur] loads retired
    } else {
      __builtin_amdgcn_s_waitcnt(0xF70);  // vmcnt(0)
    }
    __builtin_amdgcn_s_barrier();  // (B) Ks[cur] visible to all waves

    // V fragments for this tile, direct from global (consumed in PV below)
    f16x8 vfr[2][4];
    #pragma unroll
    for (int ks = 0; ks < 2; ++ks)
      #pragma unroll
      for (int id = 0; id < 4; ++id)
        vfr[ks][id] = *(const f16x8*)(vp + (size_t)(id * 16 + lrow) * 2048 + kt * 64 + ks * 32 + quad * 8);

    // QK phase, ik-outer (z live = 16 regs)
    #pragma unroll
    for (int ik = 0; ik < 4; ++ik) {
      f16x8 kf0 = *(const f16x8*)&Ks[cur][(ik * 16 + lrow) * 64 + ((quad) ^ sw) * 8];
      f16x8 kf1 = *(const f16x8*)&Ks[cur][(ik * 16 + lrow) * 64 + ((4 + quad) ^ sw) * 8];
      f32x4 z[4];
      #pragma unroll
      for (int iq = 0; iq < 4; ++iq)
        z[iq] = *(const f32x4*)(mp + (size_t)(iq * 16 + lrow) * 2048 + kt * 64 + ik * 16 + quad * 4);
      #pragma unroll
      for (int iq = 0; iq < 4; ++iq)
        z[iq] = __builtin_amdgcn_mfma_f32_16x16x32_f16(kf0, qf[iq][0], z[iq], 0, 0, 0);
      #pragma unroll
      for (int iq = 0; iq < 4; ++iq)
        z[iq] = __builtin_amdgcn_mfma_f32_16x16x32_f16(kf1, qf[iq][1], z[iq], 0, 0, 0);
      // exp2 + 1-instr packs -> P^T rows (wave-private, pitch 72)
      #pragma unroll
      for (int iq = 0; iq < 4; ++iq) {
        float e0 = exp2f(z[iq][0]), e1 = exp2f(z[iq][1]);
        float e2 = exp2f(z[iq][2]), e3 = exp2f(z[iq][3]);
        uint2 p;
        p.x = pk_f16(e0, e1);
        p.y = pk_f16(e2, e3);
        *(uint2*)&Ps[(w * 64 + iq * 16 + lrow) * 72 + ik * 16 + quad * 4] = p;
      }
    }
    __builtin_amdgcn_s_waitcnt(0xC07F);  // lgkmcnt(0): own P writes -> own reads

    // PV phase: O^T += V^T P^T ; l += 1^T P^T
    #pragma unroll
    for (int ks = 0; ks < 2; ++ks) {
      f16x8 pf[4];
      #pragma unroll
      for (int iq = 0; iq < 4; ++iq)
        pf[iq] = *(const f16x8*)&Ps[(w * 64 + iq * 16 + lrow) * 72 + ks * 32 + quad * 8];
      #pragma unroll
      for (int id = 0; id < 4; ++id)
        #pragma unroll
        for (int iq = 0; iq < 4; ++iq)
          o_acc[id][iq] = __builtin_amdgcn_mfma_f32_16x16x32_f16(vfr[ks][id], pf[iq], o_acc[id][iq], 0, 0, 0);
      #pragma unroll
      for (int iq = 0; iq < 4; ++iq)
        o_l[iq] = __builtin_amdgcn_mfma_f32_16x16x32_f16(ones, pf[iq], o_l[iq], 0, 0, 0);
    }
  }

  // epilogue: broadcast l, normalize, store O^T as f16
  _Float16* ob = vals + (size_t)(b * 2048 + qt2 * 256 + w * 64) * 1024 + h * 64;
  #pragma unroll
  for (int iq = 0; iq < 4; ++iq) {
    float l = __shfl(o_l[iq][0], lrow);  // l for q=iq*16+lrow lives in lane lrow
    float inv = 1.f / l;
    #pragma unroll
    for (int id = 0; id < 4; ++id) {
      uint2 p;
      p.x = pk_f16(o_acc[id][iq][0] * inv, o_acc[id][iq][1] * inv);
      p.y = pk_f16(o_acc[id][iq][2] * inv, o_acc[id][iq][3] * inv);
      *(uint2*)&ob[(size_t)(iq * 16 + lrow) * 1024 + id * 16 + quad * 4] = p;
    }
  }
}

extern "C" void kernel_launch(void* const* d_in, const int* in_sizes, int n_in,
                              void* d_out, int out_size, void* d_ws, size_t ws_size,
                              hipStream_t stream) {
  const float* x    = (const float*)d_in[0];
  const float* y    = (const float*)d_in[1];
  const float* mask = (const float*)d_in[2];
  const float* Wkv  = (const float*)d_in[3];
  const float* bkv  = (const float*)d_in[4];
  const float* Wq   = (const float*)d_in[5];
  const float* bq   = (const float*)d_in[6];
  const float* Wo   = (const float*)d_in[7];
  const float* bo   = (const float*)d_in[8];

  char* ws = (char*)d_ws;
  _Float16* xb    = (_Float16*)(ws + ((size_t)0 << 20));
  _Float16* yb    = (_Float16*)(ws + ((size_t)16 << 20));
  _Float16* wkvt  = (_Float16*)(ws + ((size_t)32 << 20));
  _Float16* wqt   = (_Float16*)(ws + ((size_t)36 << 20));
  _Float16* wot   = (_Float16*)(ws + ((size_t)38 << 20));
  _Float16* kbuf  = (_Float16*)(ws + ((size_t)40 << 20));
  _Float16* vtbuf = (_Float16*)(ws + ((size_t)56 << 20));
  _Float16* qbuf  = (_Float16*)(ws + ((size_t)72 << 20));
  _Float16* valsb = (_Float16*)(ws + ((size_t)88 << 20));
  float*    masks = (float*)   (ws + ((size_t)108 << 20));

  cast_xy<<<16384, 256, 0, stream>>>(x, y, xb, yb);
  scale_mask<<<4096, 256, 0, stream>>>(mask, masks);
  transpose_cast_all<<<4096, 256, 0, stream>>>(Wkv, Wq, Wo, wkvt, wqt, wot);

  // kv = x @ Wkv + bkv -> K[b,h,s,64], Vt[b,h,64,s]
  gemm128<1><<<dim3(16, 64), 256, 0, stream>>>(xb, wkvt, bkv, kbuf, vtbuf, 8192, 2048, 1024);
  // q = y @ Wq + bq -> Q[b,h,s,64] (pre-scaled by 0.125*log2e)
  gemm128<2><<<dim3(8, 64), 256, 0, stream>>>(yb, wqt, bq, qbuf, nullptr, 8192, 1024, 1024);
  // attention -> vals [b,s,1024] f16
  attn<<<512, 256, 0, stream>>>(qbuf, kbuf, vtbuf, masks, valsb);
  // out = vals @ Wo + bo (fp32)
  gemm128<0><<<dim3(8, 64), 256, 0, stream>>>(valsb, wot, bo, (float*)d_out, nullptr, 8192, 1024, 1024);
}